// Round 3
// 1252.978 us; speedup vs baseline: 1.3604x; 1.3604x over previous
//
#include <hip/hip_runtime.h>
#include <stdint.h>
#include <stddef.h>

// PhiMoE top-2 MoE: route -> bucket -> grouped GEMM (bf16 MFMA) -> scatter-add.
// T=1024 tokens, H=2048 hidden, I=4096 intermediate, E=8 experts.
//
// R3 = BISECT: known-good baseline (1704 us, passed) + ONLY the XCD-decode
// fix. Old decode: mtile = bx & 7 with early-exit for mtile >= ceil(cnt/128)
// (~3 of 8) -> active blocks all have bx%8 in {0,1,2} -> period-8 XCD
// round-robin parks all work on XCDs 0-2, 5/8 of the machine idle.
// New decode: mtile in HIGH bits -> active blocks form a dense prefix ->
// all 8 XCDs / 256 CUs populated. Everything else byte-identical to the
// passing baseline (single-buffered LDS, 20 KB/block, launch_bounds(256)).
// R1/R2 (dbuf pipeline) failed twice with container-level infra errors and
// no kernel-attributable evidence; this round isolates the variable.

#define Tn 1024
#define Hn 2048
#define In 4096
#define En 8

typedef __bf16 bf16x8 __attribute__((ext_vector_type(8)));
typedef float f32x4 __attribute__((ext_vector_type(4)));

static __device__ __forceinline__ uint16_t bf_rne(float f) {
  uint32_t u = __builtin_bit_cast(uint32_t, f);
  u += 0x7fffu + ((u >> 16) & 1u);
  return (uint16_t)(u >> 16);
}
// truncating fp32->bf16 pair pack (cheap: 3 VALU ops) — bias ~0.2% rel, well
// inside the 8.9e-2 abs tolerance.
static __device__ __forceinline__ uint32_t pack_trunc(float f0, float f1) {
  uint32_t u0 = __builtin_bit_cast(uint32_t, f0);
  uint32_t u1 = __builtin_bit_cast(uint32_t, f1);
  return (u0 >> 16) | (u1 & 0xffff0000u);
}

// ---------------- x -> bf16 ----------------
__global__ __launch_bounds__(256) void cvt_x_kernel(const float* __restrict__ x,
                                                    uint16_t* __restrict__ xb) {
  size_t i = ((size_t)blockIdx.x * 256 + threadIdx.x) * 8;
  float4 a = *(const float4*)(x + i);
  float4 b = *(const float4*)(x + i + 4);
  uint4 o;
  o.x = (uint32_t)bf_rne(a.x) | ((uint32_t)bf_rne(a.y) << 16);
  o.y = (uint32_t)bf_rne(a.z) | ((uint32_t)bf_rne(a.w) << 16);
  o.z = (uint32_t)bf_rne(b.x) | ((uint32_t)bf_rne(b.y) << 16);
  o.w = (uint32_t)bf_rne(b.z) | ((uint32_t)bf_rne(b.w) << 16);
  *(uint4*)(xb + i) = o;
}

// ---------------- router + sparsemixer ----------------
__global__ __launch_bounds__(256) void router_kernel(
    const float* __restrict__ x, const float* __restrict__ gw,
    int* __restrict__ sel, float* __restrict__ mult, int* __restrict__ counts) {
  __shared__ __align__(16) float xs[Hn];
  __shared__ float lg[En];
  const int t = blockIdx.x;
  for (int i = threadIdx.x; i < Hn / 4; i += 256)
    ((float4*)xs)[i] = ((const float4*)(x + (size_t)t * Hn))[i];
  __syncthreads();
  const int e = threadIdx.x >> 5;   // 32 threads per expert
  const int l = threadIdx.x & 31;
  const float* w = gw + e * Hn;
  float p = 0.f;
  for (int h = l; h < Hn; h += 32) p += xs[h] * w[h];
#pragma unroll
  for (int off = 16; off >= 1; off >>= 1) p += __shfl_down(p, off, 32);
  if (l == 0) lg[e] = p;
  __syncthreads();
  if (threadIdx.x == 0) {
    float s[En];
#pragma unroll
    for (int i = 0; i < En; i++) s[i] = lg[i];
    // top-1 (first occurrence, matches jnp.argmax)
    float max1 = s[0]; int ind1 = 0;
    for (int i = 1; i < En; i++) if (s[i] > max1) { max1 = s[i]; ind1 = i; }
    float den = 0.f;
    for (int i = 0; i < En; i++) {
      float factor = fmaxf(fabsf(s[i]), max1);
      if (!((max1 - s[i]) / factor > 0.02f)) den += expf(s[i] - max1);
    }
    // top-2 on masked scores
    float max2 = -3.4e38f; int ind2 = 0;
    for (int i = 0; i < En; i++) if (i != ind1 && s[i] > max2) { max2 = s[i]; ind2 = i; }
    float den2 = 0.f;
    for (int i = 0; i < En; i++) {
      if (i == ind1) continue;  // masked_scores = -inf there
      float factor = fmaxf(fabsf(s[i]), max2);
      if (!((max2 - s[i]) / factor > 0.02f)) den2 += expf(s[i] - max2);
    }
    sel[2 * t] = ind1; sel[2 * t + 1] = ind2;
    mult[2 * t] = 1.f / den; mult[2 * t + 1] = 1.f / den2;
    atomicAdd(&counts[ind1], 1);
    atomicAdd(&counts[ind2], 1);
  }
}

// ---------------- bucket assignments per expert ----------------
__global__ __launch_bounds__(256) void scatter_kernel(
    const int* __restrict__ sel, const float* __restrict__ mult,
    const int* __restrict__ counts, int* __restrict__ base,
    int* __restrict__ cursor, int* __restrict__ a_tok, float* __restrict__ a_mult) {
  __shared__ int sbase[En];
  if (threadIdx.x == 0) {
    int accb = 0;
    for (int e2 = 0; e2 < En; e2++) { sbase[e2] = accb; base[e2] = accb; accb += counts[e2]; }
  }
  __syncthreads();
  for (int t = threadIdx.x; t < Tn; t += 256) {
#pragma unroll
    for (int s2 = 0; s2 < 2; s2++) {
      int e2 = sel[2 * t + s2];
      int pos = sbase[e2] + atomicAdd(&cursor[e2], 1);  // cursor pre-zeroed
      a_tok[pos] = t;
      a_mult[pos] = mult[2 * t + s2];
    }
  }
}

// ---------------- GEMM1: act = silu(x@Wg^T) * (x@Wu^T), per expert ----------------
// grid = 8 mtiles * E * 64 ntiles (mtile in HIGH bits -> active blocks dense).
// Block tile: 128 tokens x (64 g-cols + 64 u-cols).
__global__ __launch_bounds__(256) void gemm1_kernel(
    const uint16_t* __restrict__ xb, const float* __restrict__ wgu,
    const int* __restrict__ a_tok, const int* __restrict__ base,
    const int* __restrict__ counts, uint16_t* __restrict__ act) {
  const int bx = blockIdx.x;
  const int mtile = bx >> 9;        // HIGH bits: 0..7
  const int r = bx & 511;
  const int e = r >> 6;
  const int ntile = r & 63;         // i-cols [ntile*64, ntile*64+64)
  const int cnt = counts[e];
  if (mtile * 128 >= cnt) return;
  const int bas = base[e];

  __shared__ __align__(16) uint16_t sA[128 * 40];  // pad 32->40 elems (16B-aligned rows)
  __shared__ __align__(16) uint16_t sB[128 * 40];

  const int tid = threadIdx.x;
  const int srow = tid >> 1;  // staged tile row 0..127
  const int seg = tid & 1;    // 16-element half of the 32-wide k-slice

  const int mrow = mtile * 128 + srow;
  const int tok = a_tok[bas + (mrow < cnt ? mrow : cnt - 1)];
  const uint16_t* aptr = xb + (size_t)tok * Hn + seg * 16;
  // B rows: j<64 -> Wg row ntile*64+j ; j>=64 -> Wu row 4096 + ntile*64 + (j-64)
  const int grow = ntile * 64 + srow + ((srow >> 6) * 4032);
  const float* bptr = wgu + (size_t)e * (2 * In) * Hn + (size_t)grow * Hn + seg * 16;

  uint16_t* sAw = &sA[srow * 40 + seg * 16];
  uint16_t* sBw = &sB[srow * 40 + seg * 16];

  const int lane = tid & 63;
  const int wv = tid >> 6;        // wave: rows [wv*32, wv*32+32), all 128 cols
  const int l15 = lane & 15;
  const int quad = lane >> 4;
  const uint16_t* sAr = &sA[(wv * 32 + l15) * 40 + quad * 8];
  const uint16_t* sBr = &sB[l15 * 40 + quad * 8];

  f32x4 acc[2][8] = {};

  for (int k0 = 0; k0 < Hn; k0 += 32) {
    uint4 av0 = *(const uint4*)(aptr + k0);
    uint4 av1 = *(const uint4*)(aptr + k0 + 8);
    float4 b0 = *(const float4*)(bptr + k0);
    float4 b1 = *(const float4*)(bptr + k0 + 4);
    float4 b2 = *(const float4*)(bptr + k0 + 8);
    float4 b3 = *(const float4*)(bptr + k0 + 12);
    __syncthreads();
    *(uint4*)sAw = av0;
    *(uint4*)(sAw + 8) = av1;
    uint4 p0, p1;
    p0.x = pack_trunc(b0.x, b0.y); p0.y = pack_trunc(b0.z, b0.w);
    p0.z = pack_trunc(b1.x, b1.y); p0.w = pack_trunc(b1.z, b1.w);
    p1.x = pack_trunc(b2.x, b2.y); p1.y = pack_trunc(b2.z, b2.w);
    p1.z = pack_trunc(b3.x, b3.y); p1.w = pack_trunc(b3.z, b3.w);
    *(uint4*)sBw = p0;
    *(uint4*)(sBw + 8) = p1;
    __syncthreads();
    bf16x8 a0 = *(const bf16x8*)sAr;
    bf16x8 a1 = *(const bf16x8*)(sAr + 16 * 40);
#pragma unroll
    for (int ni = 0; ni < 8; ni++) {
      bf16x8 bfr = *(const bf16x8*)(sBr + ni * 16 * 40);
      acc[0][ni] = __builtin_amdgcn_mfma_f32_16x16x32_bf16(a0, bfr, acc[0][ni], 0, 0, 0);
      acc[1][ni] = __builtin_amdgcn_mfma_f32_16x16x32_bf16(a1, bfr, acc[1][ni], 0, 0, 0);
    }
  }

  // epilogue: cols 0-63 = g, 64-127 = u; frag ni pairs with frag ni+4 elementwise
#pragma unroll
  for (int mi = 0; mi < 2; mi++) {
#pragma unroll
    for (int rr = 0; rr < 4; rr++) {
      int mrowg = mtile * 128 + wv * 32 + mi * 16 + quad * 4 + rr;
      if (mrowg < cnt) {
        size_t rowoff = (size_t)(bas + mrowg) * In + ntile * 64 + l15;
#pragma unroll
        for (int ni = 0; ni < 4; ni++) {
          float g = acc[mi][ni][rr];
          float u = acc[mi][ni + 4][rr];
          float a = g / (1.f + __expf(-g)) * u;
          act[rowoff + ni * 16] = bf_rne(a);
        }
      }
    }
  }
}

// ---------------- GEMM2: out[tok] += mult * (act @ w2^T) ----------------
// grid = 8 mtiles * E * 16 ntiles (mtile in HIGH bits). 128 x 128, K=4096.
__global__ __launch_bounds__(256) void gemm2_kernel(
    const uint16_t* __restrict__ act, const float* __restrict__ w2,
    const int* __restrict__ a_tok, const float* __restrict__ a_mult,
    const int* __restrict__ base, const int* __restrict__ counts,
    float* __restrict__ out) {
  const int bx = blockIdx.x;
  const int mtile = bx >> 7;        // HIGH bits: 0..7
  const int r = bx & 127;
  const int e = r >> 4;
  const int ntile = r & 15;
  const int cnt = counts[e];
  if (mtile * 128 >= cnt) return;
  const int bas = base[e];

  __shared__ __align__(16) uint16_t sA[128 * 40];
  __shared__ __align__(16) uint16_t sB[128 * 40];

  const int tid = threadIdx.x;
  const int srow = tid >> 1;
  const int seg = tid & 1;

  // padded rows beyond cnt read neighbor/garbage act rows: finite, masked at epilogue
  const uint16_t* aptr = act + (size_t)(bas + mtile * 128 + srow) * In + seg * 16;
  const float* bptr = w2 + (size_t)e * Hn * In + (size_t)(ntile * 128 + srow) * In + seg * 16;

  uint16_t* sAw = &sA[srow * 40 + seg * 16];
  uint16_t* sBw = &sB[srow * 40 + seg * 16];

  const int lane = tid & 63;
  const int wv = tid >> 6;
  const int l15 = lane & 15;
  const int quad = lane >> 4;
  const uint16_t* sAr = &sA[(wv * 32 + l15) * 40 + quad * 8];
  const uint16_t* sBr = &sB[l15 * 40 + quad * 8];

  f32x4 acc[2][8] = {};

  for (int k0 = 0; k0 < In; k0 += 32) {
    uint4 av0 = *(const uint4*)(aptr + k0);
    uint4 av1 = *(const uint4*)(aptr + k0 + 8);
    float4 b0 = *(const float4*)(bptr + k0);
    float4 b1 = *(const float4*)(bptr + k0 + 4);
    float4 b2 = *(const float4*)(bptr + k0 + 8);
    float4 b3 = *(const float4*)(bptr + k0 + 12);
    __syncthreads();
    *(uint4*)sAw = av0;
    *(uint4*)(sAw + 8) = av1;
    uint4 p0, p1;
    p0.x = pack_trunc(b0.x, b0.y); p0.y = pack_trunc(b0.z, b0.w);
    p0.z = pack_trunc(b1.x, b1.y); p0.w = pack_trunc(b1.z, b1.w);
    p1.x = pack_trunc(b2.x, b2.y); p1.y = pack_trunc(b2.z, b2.w);
    p1.z = pack_trunc(b3.x, b3.y); p1.w = pack_trunc(b3.z, b3.w);
    *(uint4*)sBw = p0;
    *(uint4*)(sBw + 8) = p1;
    __syncthreads();
    bf16x8 a0 = *(const bf16x8*)sAr;
    bf16x8 a1 = *(const bf16x8*)(sAr + 16 * 40);
#pragma unroll
    for (int ni = 0; ni < 8; ni++) {
      bf16x8 bfr = *(const bf16x8*)(sBr + ni * 16 * 40);
      acc[0][ni] = __builtin_amdgcn_mfma_f32_16x16x32_bf16(a0, bfr, acc[0][ni], 0, 0, 0);
      acc[1][ni] = __builtin_amdgcn_mfma_f32_16x16x32_bf16(a1, bfr, acc[1][ni], 0, 0, 0);
    }
  }

#pragma unroll
  for (int mi = 0; mi < 2; mi++) {
#pragma unroll
    for (int rr = 0; rr < 4; rr++) {
      int mrowg = mtile * 128 + wv * 32 + mi * 16 + quad * 4 + rr;
      if (mrowg < cnt) {
        int pos = bas + mrowg;
        int t = a_tok[pos];
        float m = a_mult[pos];
        float* orow = out + (size_t)t * Hn + ntile * 128 + l15;
#pragma unroll
        for (int ni = 0; ni < 8; ni++) {
          atomicAdd(orow + ni * 16, m * acc[mi][ni][rr]);
        }
      }
    }
  }
}

// ---------------- launch ----------------
extern "C" void kernel_launch(void* const* d_in, const int* in_sizes, int n_in,
                              void* d_out, int out_size, void* d_ws, size_t ws_size,
                              hipStream_t stream) {
  const float* x   = (const float*)d_in[0];   // (T,H)
  const float* gw  = (const float*)d_in[1];   // (E,H)
  const float* wgu = (const float*)d_in[2];   // (E,2I,H)
  const float* w2  = (const float*)d_in[3];   // (E,H,I)
  float* out = (float*)d_out;                 // (T,H) fp32

  char* p = (char*)d_ws;
  uint16_t* xb  = (uint16_t*)p;  p += (size_t)Tn * Hn * 2;          // 4 MB
  int* sel      = (int*)p;       p += Tn * 2 * sizeof(int);
  float* mult   = (float*)p;     p += Tn * 2 * sizeof(float);
  int* counts   = (int*)p;       p += En * sizeof(int);
  int* cursor   = (int*)p;       p += En * sizeof(int);             // zeroed with counts
  int* base     = (int*)p;       p += En * sizeof(int);
  int* a_tok    = (int*)p;       p += 2304 * sizeof(int);
  float* a_mult = (float*)p;     p += 2304 * sizeof(float);
  p = (char*)(((uintptr_t)p + 255) & ~(uintptr_t)255);
  uint16_t* act = (uint16_t*)p;  p += (size_t)2304 * In * 2;        // 18.9 MB

  hipMemsetAsync(counts, 0, 2 * En * sizeof(int), stream);          // counts + cursor
  hipMemsetAsync(d_out, 0, (size_t)Tn * Hn * sizeof(float), stream);

  cvt_x_kernel<<<(Tn * Hn) / (256 * 8), 256, 0, stream>>>(x, xb);
  router_kernel<<<Tn, 256, 0, stream>>>(x, gw, sel, mult, counts);
  scatter_kernel<<<1, 256, 0, stream>>>(sel, mult, counts, base, cursor, a_tok, a_mult);
  gemm1_kernel<<<8 * En * 64, 256, 0, stream>>>(xb, wgu, a_tok, base, counts, act);
  gemm2_kernel<<<8 * En * 16, 256, 0, stream>>>(act, w2, a_tok, a_mult, base, counts, out);
}